// Round 7
// baseline (213.414 us; speedup 1.0000x reference)
//
#include <hip/hip_runtime.h>
#include <math.h>

#define D_MODEL 768
#define NHEADS  12
#define HDIM    64
#define SEQ     1024
#define BATCH   8
#define NBH     (BATCH*NHEADS)          // 96
#define M_TOTAL (BATCH*SEQ)             // 8192
#define KT_D    (D_MODEL/32)            // 24
#define QKV_COLS (3*D_MODEL)            // 2304

typedef __attribute__((ext_vector_type(8))) short bf16x8;
typedef __attribute__((ext_vector_type(4))) float f32x4;

#define MFMA16(a,b,c) __builtin_amdgcn_mfma_f32_16x16x32_bf16((a),(b),(c),0,0,0)

// Q pre-scale: 1/sqrt(64) * log2(e) so softmax runs in exp2 domain
#define QSCALE 0.18033688011112042f

// ---- helpers ----------------------------------------------------------------
__device__ inline unsigned short f2bf(float f) {
    unsigned u = __float_as_uint(f);
    u += 0x7FFFu + ((u >> 16) & 1u);
    return (unsigned short)(u >> 16);
}
__device__ inline float bf2f(unsigned short h) {
    return __uint_as_float(((unsigned)h) << 16);
}
__device__ inline void split2(float x, unsigned short& hi, unsigned short& lo) {
    hi = f2bf(x);
    lo = f2bf(x - bf2f(hi));
}
__device__ inline void gload16(const void* g, const void* l) {
    __builtin_amdgcn_global_load_lds(
        (const __attribute__((address_space(1))) unsigned*)g,
        (__attribute__((address_space(3))) unsigned*)l, 16, 0, 0);
}
__device__ inline float exp2_fast(float x) {
#if __has_builtin(__builtin_amdgcn_exp2f)
    return __builtin_amdgcn_exp2f(x);
#else
    float r; asm("v_exp_f32 %0, %1" : "=v"(r) : "v"(x)); return r;
#endif
}

// Fragment containers:
//  full subtile (hi+lo): 1024 ushorts (A-frag: lane=(row%16)+((k%32)/8)*16, slot=k%8)
//  hi-only subtile:       512 ushorts

// ---- convert x (fp32 [M][K]) -> A-fragments, HI-ONLY (gemm0 is split-2) ------
__global__ __launch_bounds__(256)
void convert_a(const float* __restrict__ src, unsigned short* __restrict__ dst,
               int total)
{
    const int gid = blockIdx.x * 256 + threadIdx.x;
    if (gid >= total) return;
    const int lane = gid & 63;
    const int sub  = gid >> 6;
    const int kt = sub % KT_D;
    const int mt = sub / KT_D;
    const float* s = src + (size_t)(mt*16 + (lane & 15)) * D_MODEL + kt*32 + (lane >> 4)*8;
    float4 v0 = *(const float4*)(s);
    float4 v1 = *(const float4*)(s + 4);
    float vv[8] = {v0.x, v0.y, v0.z, v0.w, v1.x, v1.y, v1.z, v1.w};
    union { unsigned short u[8]; bf16x8 v; } H;
    #pragma unroll
    for (int i = 0; i < 8; ++i) H.u[i] = f2bf(vv[i]);
    *(bf16x8*)(dst + (size_t)sub * 512 + lane * 8) = H.v;
}

// ---- convert weights (fp32 [K][N]) -> B-fragments, full hi+lo ----------------
__global__ __launch_bounds__(256)
void convert_b(const float* __restrict__ src, unsigned short* __restrict__ dst,
               int ldN, int total)
{
    const int gid = blockIdx.x * 256 + threadIdx.x;
    if (gid >= total) return;
    const int lane = gid & 63;
    const int sub  = gid >> 6;
    const int kt = sub % KT_D;
    const int nt = sub / KT_D;
    const int n  = nt*16 + (lane & 15);
    const int k0 = kt*32 + (lane >> 4)*8;
    const float* s = src + (size_t)k0 * ldN + n;
    union { unsigned short u[8]; bf16x8 v; } H, L;
    #pragma unroll
    for (int i = 0; i < 8; ++i) split2(s[(size_t)i * ldN], H.u[i], L.u[i]);
    unsigned short* d = dst + (size_t)sub * 1024 + lane * 8;
    *(bf16x8*)(d)       = H.v;
    *(bf16x8*)(d + 512) = L.v;
}

// ---- fragment GEMM: 128x128 tile, BK=32, 4 waves, 2-phase dbuf staging -------
// Double-buffered K/V-style staging: one barrier per kt; the barrier's implicit
// vmcnt(0) drains a prefetch issued BEFORE this kt's compute -> latency hidden.
// 1-D grid, XCD swizzle: mb=(bid&7)*8+((bid>>3)&7).
// MODE 0: A hi-only, split-2 (ah*bh + ah*bl); epilogue scatters Q(full)/K(hi)/V(hi).
// MODE 1: A full, split-3; fp32 out + bias.
template<int MODE>
__global__ __launch_bounds__(256)
void gemm_frag(const unsigned short* __restrict__ Af,
               const unsigned short* __restrict__ Bf,
               const float* __restrict__ bias,
               float* __restrict__ outF,
               unsigned short* __restrict__ outQ,
               unsigned short* __restrict__ outK,
               unsigned short* __restrict__ outV)
{
    constexpr int ASUB = (MODE == 0) ? 4 : 8;          // Asm KB-units per buffer
    __shared__ unsigned short Asm[2][ASUB * 1024];
    __shared__ unsigned short Bsm[2][8 * 1024];
    const int t = threadIdx.x, lane = t & 63, wid = t >> 6;
    const int wr = wid >> 1, wc = wid & 1;
    const int bid = blockIdx.x;
    const int mb = (bid & 7) * 8 + ((bid >> 3) & 7);
    const int nb = bid >> 6;

    f32x4 acc[4][4] = {};

    // stage K-step ktv into buffer b (wave-chunked)
    auto stage = [&](int b, int ktv) {
        if (MODE == 0) {
            #pragma unroll
            for (int i = 0; i < 2; ++i) {
                const int h = i*4 + wid;       // hi-only subtile 0..7
                const unsigned short* ga = Af + ((size_t)(mb*8 + h)*KT_D + ktv)*512 + lane*8;
                gload16(ga, (const char*)&Asm[b][0] + (size_t)(i*256 + wid*64)*16);
            }
        } else {
            #pragma unroll
            for (int i = 0; i < 4; ++i) {
                const int h = i*4 + wid;       // half-chunk 0..15
                const unsigned short* ga = Af + ((size_t)(mb*8 + (h >> 1))*KT_D + ktv)*1024
                                         + (h & 1)*512 + lane*8;
                gload16(ga, (const char*)&Asm[b][0] + (size_t)(i*256 + wid*64)*16);
            }
        }
        #pragma unroll
        for (int i = 0; i < 4; ++i) {
            const int h = i*4 + wid;           // half-chunk 0..15
            const unsigned short* gb = Bf + ((size_t)(nb*8 + (h >> 1))*KT_D + ktv)*1024
                                     + (h & 1)*512 + lane*8;
            gload16(gb, (const char*)&Bsm[b][0] + (size_t)(i*256 + wid*64)*16);
        }
    };

    stage(0, 0);
    __syncthreads();                           // prologue staged (vmcnt drained)

    for (int kt = 0; kt < KT_D; ++kt) {
        const int cur = kt & 1;
        if (kt + 1 < KT_D) stage(cur ^ 1, kt + 1);   // prefetch next (hidden)

        bf16x8 bh[4], bl[4];
        #pragma unroll
        for (int n = 0; n < 4; ++n) {
            bh[n] = *(const bf16x8*)(&Bsm[cur][0] + (wc*4 + n)*1024 + lane*8);
            bl[n] = *(const bf16x8*)(&Bsm[cur][0] + (wc*4 + n)*1024 + 512 + lane*8);
        }
        if (MODE == 0) {
            bf16x8 ah[4];
            #pragma unroll
            for (int m = 0; m < 4; ++m)
                ah[m] = *(const bf16x8*)(&Asm[cur][0] + (wr*4 + m)*512 + lane*8);
            #pragma unroll
            for (int m = 0; m < 4; ++m)
                #pragma unroll
                for (int n = 0; n < 4; ++n) {
                    acc[m][n] = MFMA16(ah[m], bh[n], acc[m][n]);
                    acc[m][n] = MFMA16(ah[m], bl[n], acc[m][n]);
                }
        } else {
            bf16x8 ah[4], al[4];
            #pragma unroll
            for (int m = 0; m < 4; ++m) {
                ah[m] = *(const bf16x8*)(&Asm[cur][0] + (wr*4 + m)*1024 + lane*8);
                al[m] = *(const bf16x8*)(&Asm[cur][0] + (wr*4 + m)*1024 + 512 + lane*8);
            }
            #pragma unroll
            for (int m = 0; m < 4; ++m)
                #pragma unroll
                for (int n = 0; n < 4; ++n) {
                    acc[m][n] = MFMA16(ah[m], bh[n], acc[m][n]);
                    acc[m][n] = MFMA16(ah[m], bl[n], acc[m][n]);
                    acc[m][n] = MFMA16(al[m], bh[n], acc[m][n]);
                }
        }
        __syncthreads();   // next tile staged by all waves; this tile's reads done
    }

    const int rowW = mb*128 + wr*64;
    const int colW = nb*128 + wc*64;
    if (MODE == 1) {
        #pragma unroll
        for (int m = 0; m < 4; ++m)
            #pragma unroll
            for (int n = 0; n < 4; ++n) {
                const int col = colW + n*16 + (lane & 15);
                const float bv = bias[col];
                #pragma unroll
                for (int r = 0; r < 4; ++r) {
                    const int row = rowW + m*16 + (lane >> 4)*4 + r;
                    outF[(size_t)row * D_MODEL + col] = acc[m][n][r] + bv;
                }
            }
    } else {
        #pragma unroll
        for (int m = 0; m < 4; ++m)
            #pragma unroll
            for (int n = 0; n < 4; ++n) {
                const int col = colW + n*16 + (lane & 15);
                const int which = col / D_MODEL;
                const int c = col % D_MODEL;
                const int h = c >> 6, d = c & 63;
                const float bv = bias[col];
                #pragma unroll
                for (int r = 0; r < 4; ++r) {
                    const int row = rowW + m*16 + (lane >> 4)*4 + r;
                    const int b = row >> 10, sq = row & 1023;
                    float val = acc[m][n][r] + bv;
                    if (which == 0) {                    // Q: full hi+lo, pre-scaled
                        val *= QSCALE;
                        const int sub = (sq >> 4)*2 + (d >> 5);
                        const int lp  = (sq & 15) + (((d & 31) >> 3) << 4);
                        unsigned short hi, lo; split2(val, hi, lo);
                        unsigned short* p = outQ + (size_t)(b*NHEADS + h)*131072
                                          + (size_t)sub*1024 + lp*8 + (d & 7);
                        p[0]   = hi;
                        p[512] = lo;
                    } else if (which == 1) {             // K: hi only
                        const int sub = (sq >> 4)*2 + (d >> 5);
                        const int lp  = (sq & 15) + (((d & 31) >> 3) << 4);
                        outK[(size_t)(b*NHEADS + h)*65536
                             + (size_t)sub*512 + lp*8 + (d & 7)] = f2bf(val);
                    } else {                             // V: hi only (B-frag)
                        const int sub = (d >> 4)*32 + (sq >> 5);
                        const int lp  = (d & 15) + (((sq & 31) >> 3) << 4);
                        outV[(size_t)(b*NHEADS + h)*65536
                             + (size_t)sub*512 + lp*8 + (sq & 7)] = f2bf(val);
                    }
                }
            }
    }
}

// ---- flash attention on fragments: 4 waves x 32 q-rows, KV tiles of 64 -------
// 2-phase double-buffered K/V staging (one barrier per tile, stage latency
// hidden under compute).  K,V hi-only; QK split-2; PV hi-only.
// Rowsum via MFMA with a constant ones B-frag (l is an extra accumulator).
// LDS 48KB -> 3 blocks/CU (grid-limited anyway).  Defer-max THR=8; exp2 domain.
__global__ __launch_bounds__(256, 3)
void attn_frag(const unsigned short* __restrict__ Qf,
               const unsigned short* __restrict__ Kf,
               const unsigned short* __restrict__ Vf,
               unsigned short* __restrict__ Cf)
{
    __shared__ unsigned short Ksm[2][8 * 512];   // dbuf: 4 jn x 2 kt hi subtiles
    __shared__ unsigned short Vsm[2][8 * 512];   // dbuf: 4 dt x 2 kt2 hi subtiles
    __shared__ unsigned short Psm[4 * 2048];     // per-wave P: 4 subtiles x 512 bf16

    const int t = threadIdx.x, lane = t & 63, wid = t >> 6;
    // XCD swizzle: all 8 q-blocks of one (b,h) land on the same XCD
    const int bid = blockIdx.x;
    const int qb  = (bid >> 3) & 7;
    const int bh  = (bid & 7) * 12 + (bid >> 6);
    const int mt0 = qb*8 + wid*2;              // wave's first q-subtile (of 64)
    const size_t qBase = (size_t)bh * 131072;
    const size_t kBase = (size_t)bh * 65536;

    const int slot  = lane & 7;
    const int colg  = (lane & 15) >> 3;        // 0/1
    const int qrow0 = (lane >> 4) * 4;         // 0,4,8,12

    // stage K/V hi subtiles of kv-tile jt into buffer b (4 chunks per wave)
    auto stage = [&](int b, int jt) {
        #pragma unroll
        for (int i = 0; i < 4; ++i) {
            const int ch = wid*4 + i;
            if (ch < 8) {
                const unsigned short* gk = Kf + kBase + (size_t)(jt*8 + ch)*512;
                gload16(gk + lane*8, (const char*)&Ksm[b][0] + (size_t)ch*1024);
            } else {
                const int cv = ch - 8;                 // dt = cv>>1, kt2 = cv&1
                const unsigned short* gv = Vf + kBase
                    + (size_t)((cv >> 1)*32 + jt*2 + (cv & 1))*512;
                gload16(gv + lane*8, (const char*)&Vsm[b][0] + (size_t)cv*1024);
            }
        }
    };

    stage(0, 0);                               // prologue: tile 0 into buf 0

    // Q fragments live in registers (already scaled by QSCALE) — loads overlap
    // the prologue stage.
    bf16x8 qh[2][2], ql[2][2];
    #pragma unroll
    for (int m = 0; m < 2; ++m)
        #pragma unroll
        for (int kt = 0; kt < 2; ++kt) {
            const unsigned short* p = Qf + qBase + ((size_t)(mt0 + m)*2 + kt)*1024 + lane*8;
            qh[m][kt] = *(const bf16x8*)(p);
            ql[m][kt] = *(const bf16x8*)(p + 512);
        }

    // ones B-frag for the MFMA rowsum
    bf16x8 ones;
    #pragma unroll
    for (int i = 0; i < 8; ++i) ones[i] = (short)0x3F80;

    f32x4 out[2][4] = {};
    f32x4 lacc[2] = {};                        // rowsum accumulator (all cols equal)
    float m_run[2][4];
    #pragma unroll
    for (int m = 0; m < 2; ++m)
        #pragma unroll
        for (int r = 0; r < 4; ++r) m_run[m][r] = -INFINITY;

    unsigned short* Pw = Psm + wid * 2048;

    __syncthreads();                           // prologue stage complete

    for (int jt = 0; jt < 16; ++jt) {
        const int cur = jt & 1;
        if (jt + 1 < 16) stage(cur ^ 1, jt + 1);   // prefetch next tile (hidden)

        // S = Q K^T, split-2 (K hi only)
        f32x4 s[2][4] = {};
        #pragma unroll
        for (int jn = 0; jn < 4; ++jn)
            #pragma unroll
            for (int kt = 0; kt < 2; ++kt) {
                const bf16x8 kh = *(const bf16x8*)(&Ksm[cur][0] + (jn*2 + kt)*512 + lane*8);
                #pragma unroll
                for (int m = 0; m < 2; ++m) {
                    s[m][jn] = MFMA16(qh[m][kt], kh, s[m][jn]);
                    s[m][jn] = MFMA16(ql[m][kt], kh, s[m][jn]);
                }
            }

        // defer-max: in-lane partial max -> wave-uniform skip predicate
        float mx[2][4];
        int ok = 1;
        #pragma unroll
        for (int m = 0; m < 2; ++m)
            #pragma unroll
            for (int r = 0; r < 4; ++r) {
                const float v = fmaxf(fmaxf(s[m][0][r], s[m][1][r]),
                                      fmaxf(s[m][2][r], s[m][3][r]));
                mx[m][r] = v;
                ok &= (v <= m_run[m][r] + 8.0f);
            }
        if (!__all(ok)) {
            float alf[2][4];
            #pragma unroll
            for (int m = 0; m < 2; ++m)
                #pragma unroll
                for (int r = 0; r < 4; ++r) {
                    float v = mx[m][r];
                    #pragma unroll
                    for (int msk = 1; msk < 16; msk <<= 1)
                        v = fmaxf(v, __shfl_xor(v, msk));
                    const float mn = fmaxf(m_run[m][r], v);
                    const float a  = exp2_fast(m_run[m][r] - mn);
                    m_run[m][r] = mn;
                    alf[m][r] = a;
                }
            #pragma unroll
            for (int m = 0; m < 2; ++m) {
                #pragma unroll
                for (int dt = 0; dt < 4; ++dt)
                    #pragma unroll
                    for (int r = 0; r < 4; ++r)
                        out[m][dt][r] *= alf[m][r];
                #pragma unroll
                for (int r = 0; r < 4; ++r)
                    lacc[m][r] *= alf[m][r];
            }
        }

        // P = exp2(s - m) -> bf16-hi into swizzled A-frag LDS (wave-local)
        #pragma unroll
        for (int m = 0; m < 2; ++m)
            #pragma unroll
            for (int r = 0; r < 4; ++r) {
                const float mb_ = m_run[m][r];
                const int tl   = qrow0 + r + (colg << 4);
                const int idxb = ((tl << 3) | slot) ^ (tl & 0x18);
                #pragma unroll
                for (int jn = 0; jn < 4; ++jn)
                    Pw[(m*2 + (jn >> 1))*512 + idxb + ((jn & 1) << 8)]
                        = f2bf(exp2_fast(s[m][jn][r] - mb_));
            }

        // PV + MFMA rowsum: read P back as bf16x8 A-frags (wave-local)
        const int rdswz = (lane*8) ^ (lane & 0x18);
        #pragma unroll
        for (int kt2 = 0; kt2 < 2; ++kt2) {
            bf16x8 pa[2];
            #pragma unroll
            for (int m = 0; m < 2; ++m)
                pa[m] = *(const bf16x8*)(Pw + (m*2 + kt2)*512 + rdswz);
            #pragma unroll
            for (int dt = 0; dt < 4; ++dt) {
                const bf16x8 vh = *(const bf16x8*)(&Vsm[cur][0] + (dt*2 + kt2)*512 + lane*8);
                #pragma unroll
                for (int m = 0; m < 2; ++m)
                    out[m][dt] = MFMA16(pa[m], vh, out[m][dt]);
            }
            #pragma unroll
            for (int m = 0; m < 2; ++m)
                lacc[m] = MFMA16(pa[m], ones, lacc[m]);
        }

        __syncthreads();   // next tile staged by ALL waves; this tile's reads done
    }

    // epilogue: ctx / l  ->  proj-GEMM A-fragments (full hi+lo)
    const int b = bh / NHEADS, h = bh % NHEADS;
    #pragma unroll
    for (int m = 0; m < 2; ++m)
        #pragma unroll
        for (int r = 0; r < 4; ++r) {
            const float inv = 1.0f / lacc[m][r];
            const int sq = (mt0 + m)*16 + qrow0 + r;
            const int mrow = b*SEQ + sq;
            #pragma unroll
            for (int dt = 0; dt < 4; ++dt) {
                const int c = h*64 + dt*16 + (lane & 15);
                const float val = out[m][dt][r] * inv;
                unsigned short hi, lo; split2(val, hi, lo);
                unsigned short* p = Cf + ((size_t)(mrow >> 4)*KT_D + (c >> 5))*1024
                                  + ((mrow & 15) + (((c & 31) >> 3) << 4))*8 + (c & 7);
                p[0]   = hi;
                p[512] = lo;
            }
        }
}

// ---------------------------------------------------------------------------
extern "C" void kernel_launch(void* const* d_in, const int* in_sizes, int n_in,
                              void* d_out, int out_size, void* d_ws, size_t ws_size,
                              hipStream_t stream)
{
    const float* x      = (const float*)d_in[0];
    const float* w_qkv  = (const float*)d_in[1];
    const float* b_qkv  = (const float*)d_in[2];
    const float* w_proj = (const float*)d_in[3];
    const float* b_proj = (const float*)d_in[4];
    float* out = (float*)d_out;

    unsigned short* ws = (unsigned short*)d_ws;
    unsigned short* Xf = ws;                    // 12288 sub * 512    =  6,291,456
    unsigned short* Wq = Xf + 6291456;          // 3456 sub * 1024    =  3,538,944
    unsigned short* Wp = Wq + 3538944;          // 1152 sub * 1024    =  1,179,648
    unsigned short* Qf = Wp + 1179648;          // 96 * 131072        = 12,582,912
    unsigned short* Kf = Qf + 12582912;         // 96 * 65536         =  6,291,456
    unsigned short* Vf = Kf + 6291456;          // 96 * 65536         =  6,291,456
    unsigned short* Cf = Vf + 6291456;          // 12288 sub * 1024   = 12,582,912
    // total ~49.7M ushorts = ~95 MB of d_ws

    convert_a<<<dim3(3072), 256, 0, stream>>>(x, Xf, 786432);
    convert_b<<<dim3(864),  256, 0, stream>>>(w_qkv, Wq, QKV_COLS, 221184);
    convert_b<<<dim3(288),  256, 0, stream>>>(w_proj, Wp, D_MODEL, 73728);

    gemm_frag<0><<<dim3(1152), 256, 0, stream>>>(Xf, Wq, b_qkv, nullptr, Qf, Kf, Vf);
    attn_frag<<<dim3(768), 256, 0, stream>>>(Qf, Kf, Vf, Cf);
    gemm_frag<1><<<dim3(384), 256, 0, stream>>>(Cf, Wp, b_proj, out,
                                                nullptr, nullptr, nullptr);
}

// Round 8
// 194.909 us; speedup vs baseline: 1.0949x; 1.0949x over previous
//
#include <hip/hip_runtime.h>
#include <math.h>

#define D_MODEL 768
#define NHEADS  12
#define HDIM    64
#define SEQ     1024
#define BATCH   8
#define NBH     (BATCH*NHEADS)          // 96
#define M_TOTAL (BATCH*SEQ)             // 8192
#define KT_D    (D_MODEL/32)            // 24
#define QKV_COLS (3*D_MODEL)            // 2304

typedef __attribute__((ext_vector_type(8))) short bf16x8;
typedef __attribute__((ext_vector_type(4))) float f32x4;

#define MFMA16(a,b,c) __builtin_amdgcn_mfma_f32_16x16x32_bf16((a),(b),(c),0,0,0)

// Q pre-scale: 1/sqrt(64) * log2(e) so softmax runs in exp2 domain
#define QSCALE 0.18033688011112042f

// ---- helpers ----------------------------------------------------------------
__device__ inline unsigned short f2bf(float f) {
    unsigned u = __float_as_uint(f);
    u += 0x7FFFu + ((u >> 16) & 1u);
    return (unsigned short)(u >> 16);
}
__device__ inline float bf2f(unsigned short h) {
    return __uint_as_float(((unsigned)h) << 16);
}
__device__ inline void split2(float x, unsigned short& hi, unsigned short& lo) {
    hi = f2bf(x);
    lo = f2bf(x - bf2f(hi));
}
__device__ inline void gload16(const void* g, const void* l) {
    __builtin_amdgcn_global_load_lds(
        (const __attribute__((address_space(1))) unsigned*)g,
        (__attribute__((address_space(3))) unsigned*)l, 16, 0, 0);
}
__device__ inline float exp2_fast(float x) {
#if __has_builtin(__builtin_amdgcn_exp2f)
    return __builtin_amdgcn_exp2f(x);
#else
    float r; asm("v_exp_f32 %0, %1" : "=v"(r) : "v"(x)); return r;
#endif
}

// Fragment containers:
//  full subtile (hi+lo): 1024 ushorts (A-frag: lane=(row%16)+((k%32)/8)*16, slot=k%8)
//  hi-only subtile:       512 ushorts

// ---- convert x (fp32 [M][K]) -> A-fragments, HI-ONLY (gemm0 is split-2) ------
__global__ __launch_bounds__(256)
void convert_a(const float* __restrict__ src, unsigned short* __restrict__ dst,
               int total)
{
    const int gid = blockIdx.x * 256 + threadIdx.x;
    if (gid >= total) return;
    const int lane = gid & 63;
    const int sub  = gid >> 6;
    const int kt = sub % KT_D;
    const int mt = sub / KT_D;
    const float* s = src + (size_t)(mt*16 + (lane & 15)) * D_MODEL + kt*32 + (lane >> 4)*8;
    float4 v0 = *(const float4*)(s);
    float4 v1 = *(const float4*)(s + 4);
    float vv[8] = {v0.x, v0.y, v0.z, v0.w, v1.x, v1.y, v1.z, v1.w};
    union { unsigned short u[8]; bf16x8 v; } H;
    #pragma unroll
    for (int i = 0; i < 8; ++i) H.u[i] = f2bf(vv[i]);
    *(bf16x8*)(dst + (size_t)sub * 512 + lane * 8) = H.v;
}

// ---- convert weights (fp32 [K][N]) -> B-fragments, full hi+lo ----------------
__global__ __launch_bounds__(256)
void convert_b(const float* __restrict__ src, unsigned short* __restrict__ dst,
               int ldN, int total)
{
    const int gid = blockIdx.x * 256 + threadIdx.x;
    if (gid >= total) return;
    const int lane = gid & 63;
    const int sub  = gid >> 6;
    const int kt = sub % KT_D;
    const int nt = sub / KT_D;
    const int n  = nt*16 + (lane & 15);
    const int k0 = kt*32 + (lane >> 4)*8;
    const float* s = src + (size_t)k0 * ldN + n;
    union { unsigned short u[8]; bf16x8 v; } H, L;
    #pragma unroll
    for (int i = 0; i < 8; ++i) split2(s[(size_t)i * ldN], H.u[i], L.u[i]);
    unsigned short* d = dst + (size_t)sub * 1024 + lane * 8;
    *(bf16x8*)(d)       = H.v;
    *(bf16x8*)(d + 512) = L.v;
}

// ---- fragment GEMM: 128x128 tile, BK=32, 4 waves, counted-vmcnt pipeline -----
// T4 mechanism: raw s_barrier + literal s_waitcnt vmcnt(N) — prefetched loads
// stay in flight ACROSS barriers; the wait only covers loads issued 1 (MODE1)
// or 2 (MODE0) iterations earlier, so staging latency is fully pipelined.
// MODE 0: 3 buffers, depth-2, vmcnt(12); A hi-only split-2; scatters Q/K/V frags.
// MODE 1: 2 buffers, depth-1, vmcnt(8); A full split-3; fp32 out + bias.
// 1-D grid, XCD swizzle: mb=(bid&7)*8+((bid>>3)&7).
template<int MODE>
__global__ __launch_bounds__(256)
void gemm_frag(const unsigned short* __restrict__ Af,
               const unsigned short* __restrict__ Bf,
               const float* __restrict__ bias,
               float* __restrict__ outF,
               unsigned short* __restrict__ outQ,
               unsigned short* __restrict__ outK,
               unsigned short* __restrict__ outV)
{
    constexpr int NBUF = (MODE == 0) ? 3 : 2;
    constexpr int ABUF = ((MODE == 0) ? 4 : 8) * 1024;   // ushorts per A buffer
    constexpr int BBUF = 8 * 1024;                       // ushorts per B buffer
    __shared__ unsigned short Asm[NBUF][ABUF];
    __shared__ unsigned short Bsm[NBUF][BBUF];
    const int t = threadIdx.x, lane = t & 63, wid = t >> 6;
    const int wr = wid >> 1, wc = wid & 1;
    const int bid = blockIdx.x;
    const int mb = (bid & 7) * 8 + ((bid >> 3) & 7);
    const int nb = bid >> 6;

    f32x4 acc[4][4] = {};

    // stage K-step ktv into buffer b (wave-chunked; 6 loads/wave MODE0, 8 MODE1)
    auto stage = [&](int b, int ktv) {
        if (MODE == 0) {
            #pragma unroll
            for (int i = 0; i < 2; ++i) {
                const int h = i*4 + wid;       // hi-only subtile 0..7
                const unsigned short* ga = Af + ((size_t)(mb*8 + h)*KT_D + ktv)*512 + lane*8;
                gload16(ga, (const char*)&Asm[b][0] + (size_t)(i*256 + wid*64)*16);
            }
        } else {
            #pragma unroll
            for (int i = 0; i < 4; ++i) {
                const int h = i*4 + wid;       // half-chunk 0..15
                const unsigned short* ga = Af + ((size_t)(mb*8 + (h >> 1))*KT_D + ktv)*1024
                                         + (h & 1)*512 + lane*8;
                gload16(ga, (const char*)&Asm[b][0] + (size_t)(i*256 + wid*64)*16);
            }
        }
        #pragma unroll
        for (int i = 0; i < 4; ++i) {
            const int h = i*4 + wid;           // half-chunk 0..15
            const unsigned short* gb = Bf + ((size_t)(nb*8 + (h >> 1))*KT_D + ktv)*1024
                                     + (h & 1)*512 + lane*8;
            gload16(gb, (const char*)&Bsm[b][0] + (size_t)(i*256 + wid*64)*16);
        }
    };

    // prologue: fill the pipeline
    stage(0, 0);
    if (MODE == 0) stage(1, 1);

    for (int kt = 0; kt < KT_D; ++kt) {
        const int cur = kt % NBUF;
        if (MODE == 0) {
            if (kt + 2 < KT_D) {
                stage((kt + 2) % NBUF, kt + 2);
                asm volatile("s_waitcnt vmcnt(12)" ::: "memory");  // buf[cur] landed
            } else if (kt + 1 < KT_D) {
                asm volatile("s_waitcnt vmcnt(6)" ::: "memory");
            } else {
                asm volatile("s_waitcnt vmcnt(0)" ::: "memory");
            }
        } else {
            if (kt + 1 < KT_D) {
                stage((kt + 1) % NBUF, kt + 1);
                asm volatile("s_waitcnt vmcnt(8)" ::: "memory");   // buf[cur] landed
            } else {
                asm volatile("s_waitcnt vmcnt(0)" ::: "memory");
            }
        }
        __builtin_amdgcn_s_barrier();          // all waves' chunks of buf[cur] ready

        bf16x8 bh[4], bl[4];
        #pragma unroll
        for (int n = 0; n < 4; ++n) {
            bh[n] = *(const bf16x8*)(&Bsm[cur][0] + (wc*4 + n)*1024 + lane*8);
            bl[n] = *(const bf16x8*)(&Bsm[cur][0] + (wc*4 + n)*1024 + 512 + lane*8);
        }
        if (MODE == 0) {
            bf16x8 ah[4];
            #pragma unroll
            for (int m = 0; m < 4; ++m)
                ah[m] = *(const bf16x8*)(&Asm[cur][0] + (wr*4 + m)*512 + lane*8);
            #pragma unroll
            for (int m = 0; m < 4; ++m)
                #pragma unroll
                for (int n = 0; n < 4; ++n) {
                    acc[m][n] = MFMA16(ah[m], bh[n], acc[m][n]);
                    acc[m][n] = MFMA16(ah[m], bl[n], acc[m][n]);
                }
        } else {
            bf16x8 ah[4], al[4];
            #pragma unroll
            for (int m = 0; m < 4; ++m) {
                ah[m] = *(const bf16x8*)(&Asm[cur][0] + (wr*4 + m)*1024 + lane*8);
                al[m] = *(const bf16x8*)(&Asm[cur][0] + (wr*4 + m)*1024 + 512 + lane*8);
            }
            #pragma unroll
            for (int m = 0; m < 4; ++m)
                #pragma unroll
                for (int n = 0; n < 4; ++n) {
                    acc[m][n] = MFMA16(ah[m], bh[n], acc[m][n]);
                    acc[m][n] = MFMA16(ah[m], bl[n], acc[m][n]);
                    acc[m][n] = MFMA16(al[m], bh[n], acc[m][n]);
                }
        }
        __builtin_amdgcn_s_barrier();          // reads of buf[cur] done -> reusable
    }

    const int rowW = mb*128 + wr*64;
    const int colW = nb*128 + wc*64;
    if (MODE == 1) {
        #pragma unroll
        for (int m = 0; m < 4; ++m)
            #pragma unroll
            for (int n = 0; n < 4; ++n) {
                const int col = colW + n*16 + (lane & 15);
                const float bv = bias[col];
                #pragma unroll
                for (int r = 0; r < 4; ++r) {
                    const int row = rowW + m*16 + (lane >> 4)*4 + r;
                    outF[(size_t)row * D_MODEL + col] = acc[m][n][r] + bv;
                }
            }
    } else {
        #pragma unroll
        for (int m = 0; m < 4; ++m)
            #pragma unroll
            for (int n = 0; n < 4; ++n) {
                const int col = colW + n*16 + (lane & 15);
                const int which = col / D_MODEL;
                const int c = col % D_MODEL;
                const int h = c >> 6, d = c & 63;
                const float bv = bias[col];
                #pragma unroll
                for (int r = 0; r < 4; ++r) {
                    const int row = rowW + m*16 + (lane >> 4)*4 + r;
                    const int b = row >> 10, sq = row & 1023;
                    float val = acc[m][n][r] + bv;
                    if (which == 0) {                    // Q: full hi+lo, pre-scaled
                        val *= QSCALE;
                        const int sub = (sq >> 4)*2 + (d >> 5);
                        const int lp  = (sq & 15) + (((d & 31) >> 3) << 4);
                        unsigned short hi, lo; split2(val, hi, lo);
                        unsigned short* p = outQ + (size_t)(b*NHEADS + h)*131072
                                          + (size_t)sub*1024 + lp*8 + (d & 7);
                        p[0]   = hi;
                        p[512] = lo;
                    } else if (which == 1) {             // K: hi only
                        const int sub = (sq >> 4)*2 + (d >> 5);
                        const int lp  = (sq & 15) + (((d & 31) >> 3) << 4);
                        outK[(size_t)(b*NHEADS + h)*65536
                             + (size_t)sub*512 + lp*8 + (d & 7)] = f2bf(val);
                    } else {                             // V: hi only (B-frag)
                        const int sub = (d >> 4)*32 + (sq >> 5);
                        const int lp  = (d & 15) + (((sq & 31) >> 3) << 4);
                        outV[(size_t)(b*NHEADS + h)*65536
                             + (size_t)sub*512 + lp*8 + (sq & 7)] = f2bf(val);
                    }
                }
            }
    }
}

// ---- flash attention on fragments: 4 waves x 32 q-rows, KV tiles of 64 -------
// 2-phase double-buffered K/V staging (one barrier per tile, stage latency
// hidden under the long compute phase).  K,V hi-only; QK split-2; PV hi-only.
// Rowsum via MFMA with a constant ones B-frag (l is an extra accumulator).
// LDS 48KB -> 3 blocks/CU (grid-limited anyway).  Defer-max THR=8; exp2 domain.
__global__ __launch_bounds__(256, 3)
void attn_frag(const unsigned short* __restrict__ Qf,
               const unsigned short* __restrict__ Kf,
               const unsigned short* __restrict__ Vf,
               unsigned short* __restrict__ Cf)
{
    __shared__ unsigned short Ksm[2][8 * 512];   // dbuf: 4 jn x 2 kt hi subtiles
    __shared__ unsigned short Vsm[2][8 * 512];   // dbuf: 4 dt x 2 kt2 hi subtiles
    __shared__ unsigned short Psm[4 * 2048];     // per-wave P: 4 subtiles x 512 bf16

    const int t = threadIdx.x, lane = t & 63, wid = t >> 6;
    // XCD swizzle: all 8 q-blocks of one (b,h) land on the same XCD
    const int bid = blockIdx.x;
    const int qb  = (bid >> 3) & 7;
    const int bh  = (bid & 7) * 12 + (bid >> 6);
    const int mt0 = qb*8 + wid*2;              // wave's first q-subtile (of 64)
    const size_t qBase = (size_t)bh * 131072;
    const size_t kBase = (size_t)bh * 65536;

    const int slot  = lane & 7;
    const int colg  = (lane & 15) >> 3;        // 0/1
    const int qrow0 = (lane >> 4) * 4;         // 0,4,8,12

    // stage K/V hi subtiles of kv-tile jt into buffer b (4 chunks per wave)
    auto stage = [&](int b, int jt) {
        #pragma unroll
        for (int i = 0; i < 4; ++i) {
            const int ch = wid*4 + i;
            if (ch < 8) {
                const unsigned short* gk = Kf + kBase + (size_t)(jt*8 + ch)*512;
                gload16(gk + lane*8, (const char*)&Ksm[b][0] + (size_t)ch*1024);
            } else {
                const int cv = ch - 8;                 // dt = cv>>1, kt2 = cv&1
                const unsigned short* gv = Vf + kBase
                    + (size_t)((cv >> 1)*32 + jt*2 + (cv & 1))*512;
                gload16(gv + lane*8, (const char*)&Vsm[b][0] + (size_t)cv*1024);
            }
        }
    };

    stage(0, 0);                               // prologue: tile 0 into buf 0

    // Q fragments live in registers (already scaled by QSCALE) — loads overlap
    // the prologue stage.
    bf16x8 qh[2][2], ql[2][2];
    #pragma unroll
    for (int m = 0; m < 2; ++m)
        #pragma unroll
        for (int kt = 0; kt < 2; ++kt) {
            const unsigned short* p = Qf + qBase + ((size_t)(mt0 + m)*2 + kt)*1024 + lane*8;
            qh[m][kt] = *(const bf16x8*)(p);
            ql[m][kt] = *(const bf16x8*)(p + 512);
        }

    // ones B-frag for the MFMA rowsum
    bf16x8 ones;
    #pragma unroll
    for (int i = 0; i < 8; ++i) ones[i] = (short)0x3F80;

    f32x4 out[2][4] = {};
    f32x4 lacc[2] = {};                        // rowsum accumulator (all cols equal)
    float m_run[2][4];
    #pragma unroll
    for (int m = 0; m < 2; ++m)
        #pragma unroll
        for (int r = 0; r < 4; ++r) m_run[m][r] = -INFINITY;

    unsigned short* Pw = Psm + wid * 2048;

    __syncthreads();                           // prologue stage complete

    for (int jt = 0; jt < 16; ++jt) {
        const int cur = jt & 1;
        if (jt + 1 < 16) stage(cur ^ 1, jt + 1);   // prefetch next tile (hidden)

        // S = Q K^T, split-2 (K hi only)
        f32x4 s[2][4] = {};
        #pragma unroll
        for (int jn = 0; jn < 4; ++jn)
            #pragma unroll
            for (int kt = 0; kt < 2; ++kt) {
                const bf16x8 kh = *(const bf16x8*)(&Ksm[cur][0] + (jn*2 + kt)*512 + lane*8);
                #pragma unroll
                for (int m = 0; m < 2; ++m) {
                    s[m][jn] = MFMA16(qh[m][kt], kh, s[m][jn]);
                    s[m][jn] = MFMA16(ql[m][kt], kh, s[m][jn]);
                }
            }

        // defer-max: in-lane partial max -> wave-uniform skip predicate
        float mx[2][4];
        int ok = 1;
        #pragma unroll
        for (int m = 0; m < 2; ++m)
            #pragma unroll
            for (int r = 0; r < 4; ++r) {
                const float v = fmaxf(fmaxf(s[m][0][r], s[m][1][r]),
                                      fmaxf(s[m][2][r], s[m][3][r]));
                mx[m][r] = v;
                ok &= (v <= m_run[m][r] + 8.0f);
            }
        if (!__all(ok)) {
            float alf[2][4];
            #pragma unroll
            for (int m = 0; m < 2; ++m)
                #pragma unroll
                for (int r = 0; r < 4; ++r) {
                    float v = mx[m][r];
                    #pragma unroll
                    for (int msk = 1; msk < 16; msk <<= 1)
                        v = fmaxf(v, __shfl_xor(v, msk));
                    const float mn = fmaxf(m_run[m][r], v);
                    const float a  = exp2_fast(m_run[m][r] - mn);
                    m_run[m][r] = mn;
                    alf[m][r] = a;
                }
            #pragma unroll
            for (int m = 0; m < 2; ++m) {
                #pragma unroll
                for (int dt = 0; dt < 4; ++dt)
                    #pragma unroll
                    for (int r = 0; r < 4; ++r)
                        out[m][dt][r] *= alf[m][r];
                #pragma unroll
                for (int r = 0; r < 4; ++r)
                    lacc[m][r] *= alf[m][r];
            }
        }

        // P = exp2(s - m) -> bf16-hi into swizzled A-frag LDS (wave-local)
        #pragma unroll
        for (int m = 0; m < 2; ++m)
            #pragma unroll
            for (int r = 0; r < 4; ++r) {
                const float mb_ = m_run[m][r];
                const int tl   = qrow0 + r + (colg << 4);
                const int idxb = ((tl << 3) | slot) ^ (tl & 0x18);
                #pragma unroll
                for (int jn = 0; jn < 4; ++jn)
                    Pw[(m*2 + (jn >> 1))*512 + idxb + ((jn & 1) << 8)]
                        = f2bf(exp2_fast(s[m][jn][r] - mb_));
            }

        // PV + MFMA rowsum: read P back as bf16x8 A-frags (wave-local)
        const int rdswz = (lane*8) ^ (lane & 0x18);
        #pragma unroll
        for (int kt2 = 0; kt2 < 2; ++kt2) {
            bf16x8 pa[2];
            #pragma unroll
            for (int m = 0; m < 2; ++m)
                pa[m] = *(const bf16x8*)(Pw + (m*2 + kt2)*512 + rdswz);
            #pragma unroll
            for (int dt = 0; dt < 4; ++dt) {
                const bf16x8 vh = *(const bf16x8*)(&Vsm[cur][0] + (dt*2 + kt2)*512 + lane*8);
                #pragma unroll
                for (int m = 0; m < 2; ++m)
                    out[m][dt] = MFMA16(pa[m], vh, out[m][dt]);
            }
            #pragma unroll
            for (int m = 0; m < 2; ++m)
                lacc[m] = MFMA16(pa[m], ones, lacc[m]);
        }

        __syncthreads();   // next tile staged by ALL waves; this tile's reads done
    }

    // epilogue: ctx / l  ->  proj-GEMM A-fragments (full hi+lo)
    const int b = bh / NHEADS, h = bh % NHEADS;
    #pragma unroll
    for (int m = 0; m < 2; ++m)
        #pragma unroll
        for (int r = 0; r < 4; ++r) {
            const float inv = 1.0f / lacc[m][r];
            const int sq = (mt0 + m)*16 + qrow0 + r;
            const int mrow = b*SEQ + sq;
            #pragma unroll
            for (int dt = 0; dt < 4; ++dt) {
                const int c = h*64 + dt*16 + (lane & 15);
                const float val = out[m][dt][r] * inv;
                unsigned short hi, lo; split2(val, hi, lo);
                unsigned short* p = Cf + ((size_t)(mrow >> 4)*KT_D + (c >> 5))*1024
                                  + ((mrow & 15) + (((c & 31) >> 3) << 4))*8 + (c & 7);
                p[0]   = hi;
                p[512] = lo;
            }
        }
}

// ---------------------------------------------------------------------------
extern "C" void kernel_launch(void* const* d_in, const int* in_sizes, int n_in,
                              void* d_out, int out_size, void* d_ws, size_t ws_size,
                              hipStream_t stream)
{
    const float* x      = (const float*)d_in[0];
    const float* w_qkv  = (const float*)d_in[1];
    const float* b_qkv  = (const float*)d_in[2];
    const float* w_proj = (const float*)d_in[3];
    const float* b_proj = (const float*)d_in[4];
    float* out = (float*)d_out;

    unsigned short* ws = (unsigned short*)d_ws;
    unsigned short* Xf = ws;                    // 12288 sub * 512    =  6,291,456
    unsigned short* Wq = Xf + 6291456;          // 3456 sub * 1024    =  3,538,944
    unsigned short* Wp = Wq + 3538944;          // 1152 sub * 1024    =  1,179,648
    unsigned short* Qf = Wp + 1179648;          // 96 * 131072        = 12,582,912
    unsigned short* Kf = Qf + 12582912;         // 96 * 65536         =  6,291,456
    unsigned short* Vf = Kf + 6291456;          // 96 * 65536         =  6,291,456
    unsigned short* Cf = Vf + 6291456;          // 12288 sub * 1024   = 12,582,912
    // total ~49.7M ushorts = ~95 MB of d_ws

    convert_a<<<dim3(3072), 256, 0, stream>>>(x, Xf, 786432);
    convert_b<<<dim3(864),  256, 0, stream>>>(w_qkv, Wq, QKV_COLS, 221184);
    convert_b<<<dim3(288),  256, 0, stream>>>(w_proj, Wp, D_MODEL, 73728);

    gemm_frag<0><<<dim3(1152), 256, 0, stream>>>(Xf, Wq, b_qkv, nullptr, Qf, Kf, Vf);
    attn_frag<<<dim3(768), 256, 0, stream>>>(Qf, Kf, Vf, Cf);
    gemm_frag<1><<<dim3(384), 256, 0, stream>>>(Cf, Wp, b_proj, out,
                                                nullptr, nullptr, nullptr);
}

// Round 9
// 174.547 us; speedup vs baseline: 1.2227x; 1.1167x over previous
//
#include <hip/hip_runtime.h>
#include <math.h>

#define D_MODEL 768
#define NHEADS  12
#define HDIM    64
#define SEQ     1024
#define BATCH   8
#define NBH     (BATCH*NHEADS)          // 96
#define M_TOTAL (BATCH*SEQ)             // 8192
#define KT_D    (D_MODEL/32)            // 24
#define QKV_COLS (3*D_MODEL)            // 2304

typedef __attribute__((ext_vector_type(8))) short bf16x8;
typedef __attribute__((ext_vector_type(4))) float f32x4;

#define MFMA16(a,b,c) __builtin_amdgcn_mfma_f32_16x16x32_bf16((a),(b),(c),0,0,0)

// Q pre-scale: 1/sqrt(64) * log2(e) so softmax runs in exp2 domain
#define QSCALE 0.18033688011112042f

// ---- helpers ----------------------------------------------------------------
__device__ inline unsigned short f2bf(float f) {
    unsigned u = __float_as_uint(f);
    u += 0x7FFFu + ((u >> 16) & 1u);
    return (unsigned short)(u >> 16);
}
__device__ inline float bf2f(unsigned short h) {
    return __uint_as_float(((unsigned)h) << 16);
}
__device__ inline void split2(float x, unsigned short& hi, unsigned short& lo) {
    hi = f2bf(x);
    lo = f2bf(x - bf2f(hi));
}
__device__ inline void gload16(const void* g, const void* l) {
    __builtin_amdgcn_global_load_lds(
        (const __attribute__((address_space(1))) unsigned*)g,
        (__attribute__((address_space(3))) unsigned*)l, 16, 0, 0);
}
__device__ inline float exp2_fast(float x) {
#if __has_builtin(__builtin_amdgcn_exp2f)
    return __builtin_amdgcn_exp2f(x);
#else
    float r; asm("v_exp_f32 %0, %1" : "=v"(r) : "v"(x)); return r;
#endif
}

// Fragment containers:
//  full subtile (hi+lo): 1024 ushorts (A-frag: lane=(row%16)+((k%32)/8)*16, slot=k%8)
//  hi-only subtile:       512 ushorts

// ---- convert x (fp32 [M][K]) -> A-fragments, HI-ONLY (gemm0 is split-2) ------
__global__ __launch_bounds__(256)
void convert_a(const float* __restrict__ src, unsigned short* __restrict__ dst,
               int total)
{
    const int gid = blockIdx.x * 256 + threadIdx.x;
    if (gid >= total) return;
    const int lane = gid & 63;
    const int sub  = gid >> 6;
    const int kt = sub % KT_D;
    const int mt = sub / KT_D;
    const float* s = src + (size_t)(mt*16 + (lane & 15)) * D_MODEL + kt*32 + (lane >> 4)*8;
    float4 v0 = *(const float4*)(s);
    float4 v1 = *(const float4*)(s + 4);
    float vv[8] = {v0.x, v0.y, v0.z, v0.w, v1.x, v1.y, v1.z, v1.w};
    union { unsigned short u[8]; bf16x8 v; } H;
    #pragma unroll
    for (int i = 0; i < 8; ++i) H.u[i] = f2bf(vv[i]);
    *(bf16x8*)(dst + (size_t)sub * 512 + lane * 8) = H.v;
}

// ---- convert weights (fp32 [K][N]) -> B-fragments, full hi+lo ----------------
__global__ __launch_bounds__(256)
void convert_b(const float* __restrict__ src, unsigned short* __restrict__ dst,
               int ldN, int total)
{
    const int gid = blockIdx.x * 256 + threadIdx.x;
    if (gid >= total) return;
    const int lane = gid & 63;
    const int sub  = gid >> 6;
    const int kt = sub % KT_D;
    const int nt = sub / KT_D;
    const int n  = nt*16 + (lane & 15);
    const int k0 = kt*32 + (lane >> 4)*8;
    const float* s = src + (size_t)k0 * ldN + n;
    union { unsigned short u[8]; bf16x8 v; } H, L;
    #pragma unroll
    for (int i = 0; i < 8; ++i) split2(s[(size_t)i * ldN], H.u[i], L.u[i]);
    unsigned short* d = dst + (size_t)sub * 1024 + lane * 8;
    *(bf16x8*)(d)       = H.v;
    *(bf16x8*)(d + 512) = L.v;
}

// ---- fragment GEMM: 128x64 tile, BK=32, 4 waves (2m x 2n), wave tile 64x32 ---
// Occupancy-first: small acc (8 f32x4), __launch_bounds__(256,4) -> 4 waves/SIMD
// (16 waves/CU, ~4 blocks/CU). Simple stage->sync->compute structure (empirical
// winner over dbuf/counted at this size); inter-block TLP hides the drain.
// 1-D grid, XCD swizzle: mb=(bid&7)*8+((bid>>3)&7), nb=bid>>6.
// MODE 0: A hi-only split-2; epilogue scatters Q(full)/K(hi)/V(hi) fragments.
// MODE 1: A full split-3; fp32 out + bias.
template<int MODE>
__global__ __launch_bounds__(256, 4)
void gemm_frag(const unsigned short* __restrict__ Af,
               const unsigned short* __restrict__ Bf,
               const float* __restrict__ bias,
               float* __restrict__ outF,
               unsigned short* __restrict__ outQ,
               unsigned short* __restrict__ outK,
               unsigned short* __restrict__ outV)
{
    constexpr int ACH = (MODE == 0) ? 8 : 16;      // A 1KB-chunks per kt
    constexpr int NCH = ACH + 8;                   // + B chunks (4 subtiles full)
    __shared__ unsigned short Asm[ACH * 512];
    __shared__ unsigned short Bsm[8 * 512];
    const int t = threadIdx.x, lane = t & 63, wid = t >> 6;
    const int wr = wid >> 1, wc = wid & 1;
    const int bid = blockIdx.x;
    const int mb = (bid & 7) * 8 + ((bid >> 3) & 7);
    const int nb = bid >> 6;

    f32x4 acc[4][2] = {};

    for (int kt = 0; kt < KT_D; ++kt) {
        __syncthreads();                       // prior LDS reads done
        // stage: NCH 1KB chunks, NCH/4 per wave
        #pragma unroll
        for (int i = 0; i < NCH/4; ++i) {
            const int c = wid * (NCH/4) + i;
            const unsigned short* g;
            if (c < ACH) {
                if (MODE == 0)   // A hi-only: subtile c
                    g = Af + ((size_t)(mb*8 + c)*KT_D + kt)*512 + lane*8;
                else             // A full: subtile c>>1, plane c&1
                    g = Af + ((size_t)(mb*8 + (c >> 1))*KT_D + kt)*1024 + (c & 1)*512 + lane*8;
                gload16(g, (const char*)Asm + (size_t)c*1024);
            } else {
                const int j = c - ACH;         // B: subtile j>>1, plane j&1
                g = Bf + ((size_t)(nb*4 + (j >> 1))*KT_D + kt)*1024 + (j & 1)*512 + lane*8;
                gload16(g, (const char*)Bsm + (size_t)j*1024);
            }
        }
        __syncthreads();                       // staging complete (vmcnt drained)

        bf16x8 bh[2], bl[2];
        #pragma unroll
        for (int n = 0; n < 2; ++n) {
            bh[n] = *(const bf16x8*)(Bsm + (wc*2 + n)*1024 + lane*8);
            bl[n] = *(const bf16x8*)(Bsm + (wc*2 + n)*1024 + 512 + lane*8);
        }
        if (MODE == 0) {
            bf16x8 ah[4];
            #pragma unroll
            for (int m = 0; m < 4; ++m)
                ah[m] = *(const bf16x8*)(Asm + (wr*4 + m)*512 + lane*8);
            #pragma unroll
            for (int m = 0; m < 4; ++m)
                #pragma unroll
                for (int n = 0; n < 2; ++n) {
                    acc[m][n] = MFMA16(ah[m], bh[n], acc[m][n]);
                    acc[m][n] = MFMA16(ah[m], bl[n], acc[m][n]);
                }
        } else {
            bf16x8 ah[4], al[4];
            #pragma unroll
            for (int m = 0; m < 4; ++m) {
                ah[m] = *(const bf16x8*)(Asm + (wr*4 + m)*1024 + lane*8);
                al[m] = *(const bf16x8*)(Asm + (wr*4 + m)*1024 + 512 + lane*8);
            }
            #pragma unroll
            for (int m = 0; m < 4; ++m)
                #pragma unroll
                for (int n = 0; n < 2; ++n) {
                    acc[m][n] = MFMA16(ah[m], bh[n], acc[m][n]);
                    acc[m][n] = MFMA16(ah[m], bl[n], acc[m][n]);
                    acc[m][n] = MFMA16(al[m], bh[n], acc[m][n]);
                }
        }
    }

    const int rowW = mb*128 + wr*64;
    const int colW = nb*64 + wc*32;
    if (MODE == 1) {
        #pragma unroll
        for (int m = 0; m < 4; ++m)
            #pragma unroll
            for (int n = 0; n < 2; ++n) {
                const int col = colW + n*16 + (lane & 15);
                const float bv = bias[col];
                #pragma unroll
                for (int r = 0; r < 4; ++r) {
                    const int row = rowW + m*16 + (lane >> 4)*4 + r;
                    outF[(size_t)row * D_MODEL + col] = acc[m][n][r] + bv;
                }
            }
    } else {
        // whole block maps to ONE (which, head): nb*64 .. nb*64+63
        const int which = (nb * 64) / D_MODEL;
        const int h     = ((nb * 64) % D_MODEL) >> 6;
        #pragma unroll
        for (int m = 0; m < 4; ++m)
            #pragma unroll
            for (int n = 0; n < 2; ++n) {
                const int col = colW + n*16 + (lane & 15);
                const int d = col & 63;
                const float bv = bias[col];
                #pragma unroll
                for (int r = 0; r < 4; ++r) {
                    const int row = rowW + m*16 + (lane >> 4)*4 + r;
                    const int b = row >> 10, sq = row & 1023;
                    float val = acc[m][n][r] + bv;
                    if (which == 0) {                    // Q: full hi+lo, pre-scaled
                        val *= QSCALE;
                        const int sub = (sq >> 4)*2 + (d >> 5);
                        const int lp  = (sq & 15) + (((d & 31) >> 3) << 4);
                        unsigned short hi, lo; split2(val, hi, lo);
                        unsigned short* p = outQ + (size_t)(b*NHEADS + h)*131072
                                          + (size_t)sub*1024 + lp*8 + (d & 7);
                        p[0]   = hi;
                        p[512] = lo;
                    } else if (which == 1) {             // K: hi only
                        const int sub = (sq >> 4)*2 + (d >> 5);
                        const int lp  = (sq & 15) + (((d & 31) >> 3) << 4);
                        outK[(size_t)(b*NHEADS + h)*65536
                             + (size_t)sub*512 + lp*8 + (d & 7)] = f2bf(val);
                    } else {                             // V: hi only (B-frag)
                        const int sub = (d >> 4)*32 + (sq >> 5);
                        const int lp  = (d & 15) + (((sq & 31) >> 3) << 4);
                        outV[(size_t)(b*NHEADS + h)*65536
                             + (size_t)sub*512 + lp*8 + (sq & 7)] = f2bf(val);
                    }
                }
            }
    }
}

// ---- flash attention on fragments: 4 waves x 32 q-rows, KV tiles of 64 -------
// 2-phase double-buffered K/V staging (one barrier per tile, stage latency
// hidden under the long compute phase).  K,V hi-only; QK split-2; PV hi-only.
// Rowsum via MFMA with a constant ones B-frag (l is an extra accumulator).
// LDS 48KB -> 3 blocks/CU (grid-limited anyway).  Defer-max THR=8; exp2 domain.
__global__ __launch_bounds__(256, 3)
void attn_frag(const unsigned short* __restrict__ Qf,
               const unsigned short* __restrict__ Kf,
               const unsigned short* __restrict__ Vf,
               unsigned short* __restrict__ Cf)
{
    __shared__ unsigned short Ksm[2][8 * 512];   // dbuf: 4 jn x 2 kt hi subtiles
    __shared__ unsigned short Vsm[2][8 * 512];   // dbuf: 4 dt x 2 kt2 hi subtiles
    __shared__ unsigned short Psm[4 * 2048];     // per-wave P: 4 subtiles x 512 bf16

    const int t = threadIdx.x, lane = t & 63, wid = t >> 6;
    // XCD swizzle: all 8 q-blocks of one (b,h) land on the same XCD
    const int bid = blockIdx.x;
    const int qb  = (bid >> 3) & 7;
    const int bh  = (bid & 7) * 12 + (bid >> 6);
    const int mt0 = qb*8 + wid*2;              // wave's first q-subtile (of 64)
    const size_t qBase = (size_t)bh * 131072;
    const size_t kBase = (size_t)bh * 65536;

    const int slot  = lane & 7;
    const int colg  = (lane & 15) >> 3;        // 0/1
    const int qrow0 = (lane >> 4) * 4;         // 0,4,8,12

    // stage K/V hi subtiles of kv-tile jt into buffer b (4 chunks per wave)
    auto stage = [&](int b, int jt) {
        #pragma unroll
        for (int i = 0; i < 4; ++i) {
            const int ch = wid*4 + i;
            if (ch < 8) {
                const unsigned short* gk = Kf + kBase + (size_t)(jt*8 + ch)*512;
                gload16(gk + lane*8, (const char*)&Ksm[b][0] + (size_t)ch*1024);
            } else {
                const int cv = ch - 8;                 // dt = cv>>1, kt2 = cv&1
                const unsigned short* gv = Vf + kBase
                    + (size_t)((cv >> 1)*32 + jt*2 + (cv & 1))*512;
                gload16(gv + lane*8, (const char*)&Vsm[b][0] + (size_t)cv*1024);
            }
        }
    };

    stage(0, 0);                               // prologue: tile 0 into buf 0

    // Q fragments live in registers (already scaled by QSCALE) — loads overlap
    // the prologue stage.
    bf16x8 qh[2][2], ql[2][2];
    #pragma unroll
    for (int m = 0; m < 2; ++m)
        #pragma unroll
        for (int kt = 0; kt < 2; ++kt) {
            const unsigned short* p = Qf + qBase + ((size_t)(mt0 + m)*2 + kt)*1024 + lane*8;
            qh[m][kt] = *(const bf16x8*)(p);
            ql[m][kt] = *(const bf16x8*)(p + 512);
        }

    // ones B-frag for the MFMA rowsum
    bf16x8 ones;
    #pragma unroll
    for (int i = 0; i < 8; ++i) ones[i] = (short)0x3F80;

    f32x4 out[2][4] = {};
    f32x4 lacc[2] = {};                        // rowsum accumulator (all cols equal)
    float m_run[2][4];
    #pragma unroll
    for (int m = 0; m < 2; ++m)
        #pragma unroll
        for (int r = 0; r < 4; ++r) m_run[m][r] = -INFINITY;

    unsigned short* Pw = Psm + wid * 2048;

    __syncthreads();                           // prologue stage complete

    for (int jt = 0; jt < 16; ++jt) {
        const int cur = jt & 1;
        if (jt + 1 < 16) stage(cur ^ 1, jt + 1);   // prefetch next tile (hidden)

        // S = Q K^T, split-2 (K hi only)
        f32x4 s[2][4] = {};
        #pragma unroll
        for (int jn = 0; jn < 4; ++jn)
            #pragma unroll
            for (int kt = 0; kt < 2; ++kt) {
                const bf16x8 kh = *(const bf16x8*)(&Ksm[cur][0] + (jn*2 + kt)*512 + lane*8);
                #pragma unroll
                for (int m = 0; m < 2; ++m) {
                    s[m][jn] = MFMA16(qh[m][kt], kh, s[m][jn]);
                    s[m][jn] = MFMA16(ql[m][kt], kh, s[m][jn]);
                }
            }

        // defer-max: in-lane partial max -> wave-uniform skip predicate
        float mx[2][4];
        int ok = 1;
        #pragma unroll
        for (int m = 0; m < 2; ++m)
            #pragma unroll
            for (int r = 0; r < 4; ++r) {
                const float v = fmaxf(fmaxf(s[m][0][r], s[m][1][r]),
                                      fmaxf(s[m][2][r], s[m][3][r]));
                mx[m][r] = v;
                ok &= (v <= m_run[m][r] + 8.0f);
            }
        if (!__all(ok)) {
            float alf[2][4];
            #pragma unroll
            for (int m = 0; m < 2; ++m)
                #pragma unroll
                for (int r = 0; r < 4; ++r) {
                    float v = mx[m][r];
                    #pragma unroll
                    for (int msk = 1; msk < 16; msk <<= 1)
                        v = fmaxf(v, __shfl_xor(v, msk));
                    const float mn = fmaxf(m_run[m][r], v);
                    const float a  = exp2_fast(m_run[m][r] - mn);
                    m_run[m][r] = mn;
                    alf[m][r] = a;
                }
            #pragma unroll
            for (int m = 0; m < 2; ++m) {
                #pragma unroll
                for (int dt = 0; dt < 4; ++dt)
                    #pragma unroll
                    for (int r = 0; r < 4; ++r)
                        out[m][dt][r] *= alf[m][r];
                #pragma unroll
                for (int r = 0; r < 4; ++r)
                    lacc[m][r] *= alf[m][r];
            }
        }

        // P = exp2(s - m) -> bf16-hi into swizzled A-frag LDS (wave-local)
        #pragma unroll
        for (int m = 0; m < 2; ++m)
            #pragma unroll
            for (int r = 0; r < 4; ++r) {
                const float mb_ = m_run[m][r];
                const int tl   = qrow0 + r + (colg << 4);
                const int idxb = ((tl << 3) | slot) ^ (tl & 0x18);
                #pragma unroll
                for (int jn = 0; jn < 4; ++jn)
                    Pw[(m*2 + (jn >> 1))*512 + idxb + ((jn & 1) << 8)]
                        = f2bf(exp2_fast(s[m][jn][r] - mb_));
            }

        // PV + MFMA rowsum: read P back as bf16x8 A-frags (wave-local)
        const int rdswz = (lane*8) ^ (lane & 0x18);
        #pragma unroll
        for (int kt2 = 0; kt2 < 2; ++kt2) {
            bf16x8 pa[2];
            #pragma unroll
            for (int m = 0; m < 2; ++m)
                pa[m] = *(const bf16x8*)(Pw + (m*2 + kt2)*512 + rdswz);
            #pragma unroll
            for (int dt = 0; dt < 4; ++dt) {
                const bf16x8 vh = *(const bf16x8*)(&Vsm[cur][0] + (dt*2 + kt2)*512 + lane*8);
                #pragma unroll
                for (int m = 0; m < 2; ++m)
                    out[m][dt] = MFMA16(pa[m], vh, out[m][dt]);
            }
            #pragma unroll
            for (int m = 0; m < 2; ++m)
                lacc[m] = MFMA16(pa[m], ones, lacc[m]);
        }

        __syncthreads();   // next tile staged by ALL waves; this tile's reads done
    }

    // epilogue: ctx / l  ->  proj-GEMM A-fragments (full hi+lo)
    const int b = bh / NHEADS, h = bh % NHEADS;
    #pragma unroll
    for (int m = 0; m < 2; ++m)
        #pragma unroll
        for (int r = 0; r < 4; ++r) {
            const float inv = 1.0f / lacc[m][r];
            const int sq = (mt0 + m)*16 + qrow0 + r;
            const int mrow = b*SEQ + sq;
            #pragma unroll
            for (int dt = 0; dt < 4; ++dt) {
                const int c = h*64 + dt*16 + (lane & 15);
                const float val = out[m][dt][r] * inv;
                unsigned short hi, lo; split2(val, hi, lo);
                unsigned short* p = Cf + ((size_t)(mrow >> 4)*KT_D + (c >> 5))*1024
                                  + ((mrow & 15) + (((c & 31) >> 3) << 4))*8 + (c & 7);
                p[0]   = hi;
                p[512] = lo;
            }
        }
}

// ---------------------------------------------------------------------------
extern "C" void kernel_launch(void* const* d_in, const int* in_sizes, int n_in,
                              void* d_out, int out_size, void* d_ws, size_t ws_size,
                              hipStream_t stream)
{
    const float* x      = (const float*)d_in[0];
    const float* w_qkv  = (const float*)d_in[1];
    const float* b_qkv  = (const float*)d_in[2];
    const float* w_proj = (const float*)d_in[3];
    const float* b_proj = (const float*)d_in[4];
    float* out = (float*)d_out;

    unsigned short* ws = (unsigned short*)d_ws;
    unsigned short* Xf = ws;                    // 12288 sub * 512    =  6,291,456
    unsigned short* Wq = Xf + 6291456;          // 3456 sub * 1024    =  3,538,944
    unsigned short* Wp = Wq + 3538944;          // 1152 sub * 1024    =  1,179,648
    unsigned short* Qf = Wp + 1179648;          // 96 * 131072        = 12,582,912
    unsigned short* Kf = Qf + 12582912;         // 96 * 65536         =  6,291,456
    unsigned short* Vf = Kf + 6291456;          // 96 * 65536         =  6,291,456
    unsigned short* Cf = Vf + 6291456;          // 12288 sub * 1024   = 12,582,912
    // total ~49.7M ushorts = ~95 MB of d_ws

    convert_a<<<dim3(3072), 256, 0, stream>>>(x, Xf, 786432);
    convert_b<<<dim3(864),  256, 0, stream>>>(w_qkv, Wq, QKV_COLS, 221184);
    convert_b<<<dim3(288),  256, 0, stream>>>(w_proj, Wp, D_MODEL, 73728);

    gemm_frag<0><<<dim3(2304), 256, 0, stream>>>(Xf, Wq, b_qkv, nullptr, Qf, Kf, Vf);
    attn_frag<<<dim3(768), 256, 0, stream>>>(Qf, Kf, Vf, Cf);
    gemm_frag<1><<<dim3(768), 256, 0, stream>>>(Cf, Wp, b_proj, out,
                                                nullptr, nullptr, nullptr);
}